// Round 1
// baseline (305.978 us; speedup 1.0000x reference)
//
#include <hip/hip_runtime.h>
#include <stdint.h>

typedef __bf16 bf16x8 __attribute__((ext_vector_type(8)));
typedef float  f32x4  __attribute__((ext_vector_type(4)));

#define ATTN_SCALE 2.7621359e-3f   // 1/(sqrt(128)*sqrt(1024))
#define NEG_BIG    -3.0e38f

__device__ __forceinline__ unsigned short f2bf(float f) {
  union { float f; uint32_t u; } v; v.f = f;
  uint32_t u = v.u;
  uint32_t r = (u + 0x7FFFu + ((u >> 16) & 1u)) >> 16;   // RNE
  return (unsigned short)r;
}

__device__ __forceinline__ void load_lds16(const unsigned short* g, unsigned short* l) {
  __builtin_amdgcn_global_load_lds(
      (const __attribute__((address_space(1))) void*)g,
      (__attribute__((address_space(3))) void*)l, 16, 0, 0);
}

__device__ __forceinline__ f32x4 mfma16(bf16x8 a, bf16x8 b, f32x4 c) {
  return __builtin_amdgcn_mfma_f32_16x16x32_bf16(a, b, c, 0, 0, 0);
}

// ---------------------------------------------------------------- convert
__global__ __launch_bounds__(256) void k_cvt(const float* __restrict__ src,
                                             unsigned short* __restrict__ dst, int n4) {
  int i = blockIdx.x * 256 + threadIdx.x;
  if (i >= n4) return;
  float4 f = ((const float4*)src)[i];
  ushort4 o;
  o.x = f2bf(f.x); o.y = f2bf(f.y); o.z = f2bf(f.z); o.w = f2bf(f.w);
  ((ushort4*)dst)[i] = o;
}

// ---------------------------------------------------------------- QKV projection GEMM
// C[16384,128] = X[16384,1024] @ Wsel^T ; blockIdx.y selects {Q(scaled), K, V^T}
__global__ __launch_bounds__(256, 2) void k_proj(
    const unsigned short* __restrict__ X,    // [16384][1024] bf16
    const unsigned short* __restrict__ W,    // [3][128][1024] bf16
    unsigned short* __restrict__ Qb,         // [16384][128]
    unsigned short* __restrict__ Kb,         // [16384][128]
    unsigned short* __restrict__ Vt)         // [4][128][4096]
{
  __shared__ __align__(16) unsigned short As[128 * 32];
  __shared__ __align__(16) unsigned short Bs[128 * 32];
  const int t = threadIdx.x;
  const int mtile = blockIdx.x;          // 0..127
  const int nt = blockIdx.y;             // 0..2
  const int w = t >> 6, lane = t & 63, quad = lane >> 4, l15 = lane & 15;
  const int wm = w & 1, wn = w >> 1;

  const unsigned short* Wsel = W + nt * (128 * 1024);
  const unsigned short* Ag = X + (size_t)(mtile * 128) * 1024;

  // staging map: thread t -> row t>>2, col (t&3)*8 ; 2 issues of 64 rows
  const unsigned short* ag0 = Ag + (size_t)(t >> 2) * 1024 + (t & 3) * 8;
  const unsigned short* bg0 = Wsel + (size_t)(t >> 2) * 1024 + (t & 3) * 8;
  unsigned short* aw = &As[(t >> 6) * 512];
  unsigned short* bw = &Bs[(t >> 6) * 512];

  f32x4 acc[4][4] = {};

  for (int kt = 0; kt < 32; ++kt) {
    __syncthreads();
    const unsigned short* ak = ag0 + kt * 32;
    const unsigned short* bk = bg0 + kt * 32;
    load_lds16(ak,             aw);
    load_lds16(ak + 64 * 1024, aw + 2048);
    load_lds16(bk,             bw);
    load_lds16(bk + 64 * 1024, bw + 2048);
    __syncthreads();

    bf16x8 af[4], bfr[4];
#pragma unroll
    for (int i = 0; i < 4; ++i)
      af[i] = *(const bf16x8*)&As[(wm * 64 + i * 16 + l15) * 32 + quad * 8];
#pragma unroll
    for (int j = 0; j < 4; ++j)
      bfr[j] = *(const bf16x8*)&Bs[(wn * 64 + j * 16 + l15) * 32 + quad * 8];
#pragma unroll
    for (int i = 0; i < 4; ++i)
#pragma unroll
      for (int j = 0; j < 4; ++j)
        acc[i][j] = mfma16(af[i], bfr[j], acc[i][j]);
  }

  const int m0 = mtile * 128 + wm * 64;
#pragma unroll
  for (int i = 0; i < 4; ++i)
#pragma unroll
    for (int j = 0; j < 4; ++j)
#pragma unroll
      for (int r = 0; r < 4; ++r) {
        int m = m0 + i * 16 + quad * 4 + r;
        int n = wn * 64 + j * 16 + l15;
        float v = acc[i][j][r];
        if (nt == 0) {
          Qb[(size_t)m * 128 + n] = f2bf(v * ATTN_SCALE);
        } else if (nt == 1) {
          Kb[(size_t)m * 128 + n] = f2bf(v);
        } else {
          int bb = m >> 12, s = m & 4095;
          Vt[((size_t)bb * 128 + n) * 4096 + s] = f2bf(v);
        }
      }
}

// ---------------------------------------------------------------- flash attention
// grid (64 qtiles, 4 batch), 256 thr. Wave w: h=w&1 -> Q rows h*32.. ; p=w>>1 -> key half.
__global__ __launch_bounds__(256, 1) void k_flash(
    const unsigned short* __restrict__ Qb,   // [4][4096][128] bf16, pre-scaled
    const unsigned short* __restrict__ Kb,   // [4][4096][128] bf16
    const unsigned short* __restrict__ Vt,   // [4][128][4096] bf16
    float* __restrict__ out)                 // [4][4096][128] f32
{
  __shared__ __align__(16) unsigned short smem[64 * 128 + 128 * 64 + 4 * 32 * 32]; // 40 KB
  unsigned short* Ksh = smem;            // [64 keys][128 d]
  unsigned short* Vsh = smem + 8192;     // [128 d][64 keys]
  unsigned short* Psh = smem + 16384;    // per-wave [32 q][32 keys]
  float* Ob = (float*)smem;              // merge overlay: [64][128] f32 (32 KB)
  float* ml = (float*)(smem + 16384);    // merge overlay: [64][2] f32

  const int t = threadIdx.x;
  const int w = t >> 6, lane = t & 63, quad = lane >> 4, l15 = lane & 15;
  const int h = w & 1, p = w >> 1;
  const int qt = blockIdx.x, b = blockIdx.y;

  const unsigned short* Qg = Qb + (size_t)(b * 4096 + qt * 64 + h * 32) * 128;
  const unsigned short* Kg = Kb + (size_t)b * 4096 * 128;
  const unsigned short* Vg = Vt + (size_t)b * 128 * 4096;

  // Q fragments pinned in registers: A[m=l15][k=quad*8+j]
  bf16x8 qf[2][4];
#pragma unroll
  for (int mt = 0; mt < 2; ++mt)
#pragma unroll
    for (int kk = 0; kk < 4; ++kk)
      qf[mt][kk] = *(const bf16x8*)&Qg[(size_t)(mt * 16 + l15) * 128 + kk * 32 + quad * 8];

  f32x4 O[2][8] = {};
  float m_s[2][4], l_s[2][4];
#pragma unroll
  for (int mt = 0; mt < 2; ++mt)
#pragma unroll
    for (int r = 0; r < 4; ++r) { m_s[mt][r] = NEG_BIG; l_s[mt][r] = 0.f; }

  const unsigned short* kg0 = Kg + (size_t)(t >> 4) * 128 + (t & 15) * 8;
  const unsigned short* vg0 = Vg + (size_t)(t >> 3) * 4096 + (t & 7) * 8;
  unsigned short* kw = &Ksh[(t >> 6) * 512];
  unsigned short* vw = &Vsh[(t >> 6) * 512];

  for (int kt = 0; kt < 64; ++kt) {
    __syncthreads();
    {
      const unsigned short* kg = kg0 + (size_t)kt * 64 * 128;
#pragma unroll
      for (int it = 0; it < 4; ++it)
        load_lds16(kg + (size_t)it * 16 * 128, kw + it * 2048);
      const unsigned short* vg = vg0 + kt * 64;
#pragma unroll
      for (int it = 0; it < 4; ++it)
        load_lds16(vg + (size_t)it * 32 * 4096, vw + it * 2048);
    }
    __syncthreads();

    // S = Q K^T over this wave's 32 keys (local base p*32)
    f32x4 sc[2][2] = {};
#pragma unroll
    for (int ntk = 0; ntk < 2; ++ntk)
#pragma unroll
      for (int kk = 0; kk < 4; ++kk) {
        bf16x8 kf = *(const bf16x8*)&Ksh[(size_t)(p * 32 + ntk * 16 + l15) * 128 + kk * 32 + quad * 8];
        sc[0][ntk] = mfma16(qf[0][kk], kf, sc[0][ntk]);
        sc[1][ntk] = mfma16(qf[1][kk], kf, sc[1][ntk]);
      }

    // online softmax per (mt, reg) row; 16-lane groups hold replicated state
#pragma unroll
    for (int mt = 0; mt < 2; ++mt) {
      float al[4];
#pragma unroll
      for (int r = 0; r < 4; ++r) {
        float mx = fmaxf(sc[mt][0][r], sc[mt][1][r]);
        mx = fmaxf(mx, __shfl_xor(mx, 1));
        mx = fmaxf(mx, __shfl_xor(mx, 2));
        mx = fmaxf(mx, __shfl_xor(mx, 4));
        mx = fmaxf(mx, __shfl_xor(mx, 8));
        float mn = fmaxf(m_s[mt][r], mx);
        float a  = __expf(m_s[mt][r] - mn);
        float p0 = __expf(sc[mt][0][r] - mn);
        float p1 = __expf(sc[mt][1][r] - mn);
        float rs = p0 + p1;
        rs += __shfl_xor(rs, 1);
        rs += __shfl_xor(rs, 2);
        rs += __shfl_xor(rs, 4);
        rs += __shfl_xor(rs, 8);
        m_s[mt][r] = mn;
        l_s[mt][r] = l_s[mt][r] * a + rs;
        al[r] = a;
        int row = mt * 16 + quad * 4 + r;
        Psh[w * 1024 + row * 32 + l15]      = f2bf(p0);
        Psh[w * 1024 + row * 32 + 16 + l15] = f2bf(p1);
      }
      f32x4 av; av[0] = al[0]; av[1] = al[1]; av[2] = al[2]; av[3] = al[3];
#pragma unroll
      for (int dt = 0; dt < 8; ++dt) O[mt][dt] *= av;
    }
    __builtin_amdgcn_s_waitcnt(0);   // P writes visible to own-wave ds_reads

    // O += P V  (A = P[m=q][k=key], B = Vt[k=key][n=d])
    bf16x8 pf0 = *(const bf16x8*)&Psh[w * 1024 + (0 * 16 + l15) * 32 + quad * 8];
    bf16x8 pf1 = *(const bf16x8*)&Psh[w * 1024 + (1 * 16 + l15) * 32 + quad * 8];
#pragma unroll
    for (int dt = 0; dt < 8; ++dt) {
      bf16x8 vf = *(const bf16x8*)&Vsh[(size_t)(dt * 16 + l15) * 64 + p * 32 + quad * 8];
      O[0][dt] = mfma16(pf0, vf, O[0][dt]);
      O[1][dt] = mfma16(pf1, vf, O[1][dt]);
    }
  }

  // ---- merge the two key-half states per row ----
  __syncthreads();
  if (p == 1) {
#pragma unroll
    for (int mt = 0; mt < 2; ++mt)
#pragma unroll
      for (int r = 0; r < 4; ++r) {
        int row = h * 32 + mt * 16 + quad * 4 + r;
        ml[row * 2]     = m_s[mt][r];
        ml[row * 2 + 1] = l_s[mt][r];
#pragma unroll
        for (int dt = 0; dt < 8; ++dt)
          Ob[row * 128 + dt * 16 + l15] = O[mt][dt][r];
      }
  }
  __syncthreads();
  if (p == 0) {
    float* og = out + (size_t)(b * 4096 + qt * 64) * 128;
#pragma unroll
    for (int mt = 0; mt < 2; ++mt)
#pragma unroll
      for (int r = 0; r < 4; ++r) {
        int row = h * 32 + mt * 16 + quad * 4 + r;
        float m1 = ml[row * 2], l1 = ml[row * 2 + 1];
        float m0v = m_s[mt][r];
        float M  = fmaxf(m0v, m1);
        float a0 = __expf(m0v - M), a1 = __expf(m1 - M);
        float L  = a0 * l_s[mt][r] + a1 * l1;
        float inv = 1.0f / L;
#pragma unroll
        for (int dt = 0; dt < 8; ++dt) {
          float o = a0 * O[mt][dt][r] + a1 * Ob[row * 128 + dt * 16 + l15];
          og[(size_t)row * 128 + dt * 16 + l15] = o * inv;
        }
      }
  }
}

// ---------------------------------------------------------------- launch
extern "C" void kernel_launch(void* const* d_in, const int* in_sizes, int n_in,
                              void* d_out, int out_size, void* d_ws, size_t ws_size,
                              hipStream_t stream) {
  const float* x  = (const float*)d_in[0];   // [4,4096,1024]
  const float* Wq = (const float*)d_in[1];   // [128,1024]
  const float* Wk = (const float*)d_in[2];
  const float* Wv = (const float*)d_in[3];
  float* out = (float*)d_out;                // [4,4096,128]

  unsigned short* ws  = (unsigned short*)d_ws;
  unsigned short* xbf = ws;                   // 16,777,216 elems
  unsigned short* wbf = xbf + 16777216;       // 3*131072
  unsigned short* Qb  = wbf + 393216;         // 2,097,152
  unsigned short* Kb  = Qb + 2097152;
  unsigned short* Vt  = Kb + 2097152;         // total 44.8 MB

  k_cvt<<<16384, 256, 0, stream>>>(x,  xbf, 4194304);
  k_cvt<<<128,   256, 0, stream>>>(Wq, wbf,          32768);
  k_cvt<<<128,   256, 0, stream>>>(Wk, wbf + 131072, 32768);
  k_cvt<<<128,   256, 0, stream>>>(Wv, wbf + 262144, 32768);
  k_proj<<<dim3(128, 3), 256, 0, stream>>>(xbf, wbf, Qb, Kb, Vt);
  k_flash<<<dim3(64, 4), 256, 0, stream>>>(Qb, Kb, Vt, out);
}